// Round 8
// baseline (854.824 us; speedup 1.0000x reference)
//
#include <hip/hip_runtime.h>
#include <math.h>

#define BATCH 512
#define ITERS 1000

typedef float f32x2 __attribute__((ext_vector_type(2)));
typedef float f32x4 __attribute__((ext_vector_type(4)));

// readlane requires a WAVE-UNIFORM lane index (all uses below are constants).
__device__ __forceinline__ float rdlane(float v, int l) {
  return __int_as_float(__builtin_amdgcn_readlane(__float_as_int(v), l));
}
__device__ __forceinline__ f32x2 fma2(f32x2 a, f32x2 b, f32x2 c) {
#if __has_builtin(__builtin_elementwise_fma)
  return __builtin_elementwise_fma(a, b, c);
#else
  f32x2 r; r.x = fmaf(a.x, b.x, c.x); r.y = fmaf(a.y, b.y, c.y); return r;
#endif
}

// Register-resident Gauss-Jordan on [A|I] (32x64); lane holds column `lane`.
#define GJ32_REG(g)                                            \
  _Pragma("unroll")                                            \
  for (int k = 0; k < 32; ++k) {                               \
    float inv = 1.0f / rdlane(g[k], k);                        \
    g[k] *= inv;                                               \
    _Pragma("unroll")                                          \
    for (int ii = 0; ii < 32; ++ii) {                          \
      if (ii == k) continue;                                   \
      float f = rdlane(g[ii], k);                              \
      g[ii] = fmaf(-f, g[k], g[ii]);                           \
    }                                                          \
  }

// ONE wave per block handles TWO batch rows: lanes 0-31 -> row 2B (g=0),
// lanes 32-63 -> row 2B+1 (g=1). Lane (g,l) owns output components l and
// l+32 of its row (sD rows l, l+32 in VGPRs; Hinv row l for primal).
// x1 / (x2-b) broadcasts via LDS: 16 ds_read_b128, each half-wave reading
// its row's wave-uniform address (2-address access = conflict-free).
// Single wave => no barriers anywhere; LDS RAW is in-order per wave.
// Primal runs one iteration behind so the serial x1 write->read chain has
// no same-body turnaround.
__global__ __launch_bounds__(64, 1)
void fused_kernel(const float* __restrict__ q,
                  const float* __restrict__ bmat,
                  const float* __restrict__ P,
                  const float* __restrict__ H,
                  float* __restrict__ Xs,
                  float* __restrict__ out2) {
  __shared__ __align__(16) float hstage[64 * 34];   // H transpose staging (setup)
  __shared__ __align__(16) float sdLDS[64 * 68];    // s*D, row-major, pad 68
  __shared__ __align__(16) float hiLDS[32 * 68];    // Hinv, row-major, pad 68
  __shared__ __align__(16) float muLDS[2 * 64];     // mu per row
  __shared__ __align__(16) float x1LDS[2 * 64];     // current x1 per row
  __shared__ __align__(16) float x2LDS[2 * 64];     // current x2 - b per row

  const int lane = threadIdx.x;
  const int g = lane >> 5, l = lane & 31;
  const int r0 = 2 * blockIdx.x, rg = r0 + g;

  // ---- H row `lane` ----
  float hreg[32];
  {
    const f32x4* hp = (const f32x4*)(H + lane * 32);
    #pragma unroll
    for (int j4 = 0; j4 < 8; ++j4) {
      f32x4 t = hp[j4];
      hreg[4*j4+0] = t.x; hreg[4*j4+1] = t.y; hreg[4*j4+2] = t.z; hreg[4*j4+3] = t.w;
    }
  }

  // ================= setup (one wave, sequential, in-order LDS) =============
  // ---- Hinv = (H^T H)^-1 H^T ----
  #pragma unroll
  for (int j = 0; j < 32; ++j) hstage[lane * 34 + j] = hreg[j];
  {
    float htc[64];                        // htc[m] = H[m][l]
    #pragma unroll
    for (int m = 0; m < 64; ++m) htc[m] = hstage[m * 34 + l];
    float gB[32];
    #pragma unroll
    for (int r = 0; r < 32; ++r) {
      float a0 = 0.f, a1 = 0.f;
      #pragma unroll
      for (int m = 0; m < 64; m += 2) {
        a0 = fmaf(rdlane(hreg[r], m),     htc[m],     a0);
        a1 = fmaf(rdlane(hreg[r], m + 1), htc[m + 1], a1);
      }
      float hth = a0 + a1;                // (H^T H)[r][l]
      gB[r] = (lane < 32) ? hth : (((lane - 32) == r) ? 1.0f : 0.0f);
    }
    GJ32_REG(gB)
    #pragma unroll
    for (int r = 0; r < 32; ++r) {        // Hinv[r][lane]
      float a0 = 0.f, a1 = 0.f;
      #pragma unroll
      for (int c = 0; c < 32; c += 2) {
        a0 = fmaf(rdlane(gB[r], 32 + c),     hreg[c],     a0);
        a1 = fmaf(rdlane(gB[r], 32 + c + 1), hreg[c + 1], a1);
      }
      hiLDS[r * 68 + lane] = a0 + a1;
    }
  }

  // ---- P^-1, P^-1 H^T, D, lambda_max, s, mu (both rows) ----
  float s, mu0, mu1;
  {
    float g32[32];
    #pragma unroll
    for (int r = 0; r < 32; ++r) {
      float pv = P[r * 32 + l];
      g32[r] = (lane < 32) ? pv : (((lane - 32) == r) ? 1.0f : 0.0f);
    }
    GJ32_REG(g32)
    float pht[32];
    #pragma unroll
    for (int r = 0; r < 32; ++r) {        // (P^-1 H^T)[r][lane]
      float a0 = 0.f, a1 = 0.f;
      #pragma unroll
      for (int j = 0; j < 32; j += 2) {
        a0 = fmaf(rdlane(g32[r], 32 + j),     hreg[j],     a0);
        a1 = fmaf(rdlane(g32[r], 32 + j + 1), hreg[j + 1], a1);
      }
      pht[r] = a0 + a1;
    }
    float acc0 = 0.f, acc1 = 0.f;
    {
      const float* qp0 = q + (size_t)r0 * 32;        // wave-uniform
      const float* qp1 = qp0 + 32;
      #pragma unroll
      for (int r = 0; r < 32; ++r) {
        acc0 = fmaf(qp0[r], pht[r], acc0);
        acc1 = fmaf(qp1[r], pht[r], acc1);
      }
    }
    float dcol[64];
    #pragma unroll
    for (int r = 0; r < 64; ++r) {        // D[r][lane] (symmetric)
      float a0 = 0.f, a1 = 0.f;
      #pragma unroll
      for (int j = 0; j < 32; j += 2) {
        a0 = fmaf(rdlane(hreg[j],     r), pht[j],     a0);
        a1 = fmaf(rdlane(hreg[j + 1], r), pht[j + 1], a1);
      }
      dcol[r] = a0 + a1;
    }
    {
      float ecol[64];                     // E = D^2
      #pragma unroll
      for (int r = 0; r < 64; ++r) {
        float a0 = 0.f, a1 = 0.f;
        #pragma unroll
        for (int c = 0; c < 64; c += 2) {
          a0 = fmaf(rdlane(dcol[r], c),     dcol[c],     a0);
          a1 = fmaf(rdlane(dcol[r], c + 1), dcol[c + 1], a1);
        }
        ecol[r] = a0 + a1;
      }
      float v = 1.0f + 0.017f * (float)lane;
      #pragma unroll 1
      for (int t = 0; t < 112; ++t) {
        float a0 = 0.f, a1 = 0.f, a2 = 0.f, a3 = 0.f;
        #pragma unroll
        for (int c = 0; c < 64; c += 4) {
          a0 = fmaf(ecol[c+0], rdlane(v, c+0), a0);
          a1 = fmaf(ecol[c+1], rdlane(v, c+1), a1);
          a2 = fmaf(ecol[c+2], rdlane(v, c+2), a2);
          a3 = fmaf(ecol[c+3], rdlane(v, c+3), a3);
        }
        v = (a0 + a1) + (a2 + a3);
        if ((t & 7) == 7) {
          float n2 = v * v;
          #pragma unroll
          for (int m = 1; m < 64; m <<= 1) n2 += __shfl_xor(n2, m);
          v *= 1.0f / sqrtf(n2);
        }
      }
      float a0 = 0.f, a1 = 0.f, a2 = 0.f, a3 = 0.f;  // Rayleigh with D
      #pragma unroll
      for (int c = 0; c < 64; c += 4) {
        a0 = fmaf(dcol[c+0], rdlane(v, c+0), a0);
        a1 = fmaf(dcol[c+1], rdlane(v, c+1), a1);
        a2 = fmaf(dcol[c+2], rdlane(v, c+2), a2);
        a3 = fmaf(dcol[c+3], rdlane(v, c+3), a3);
      }
      float w = (a0 + a1) + (a2 + a3);
      float num = w * v, den = v * v;
      #pragma unroll
      for (int m = 1; m < 64; m <<= 1) {
        num += __shfl_xor(num, m);
        den += __shfl_xor(den, m);
      }
      s = den / num;                      // s = 1 / lambda_max(D)
    }
    // s*D into LDS (column write: lane holds column `lane`)
    #pragma unroll
    for (int r = 0; r < 64; ++r) sdLDS[r * 68 + lane] = s * dcol[r];
    mu0 = s * (acc0 - bmat[(size_t)r0 * 64 + lane]);
    mu1 = s * (acc1 - bmat[(size_t)r0 * 64 + 64 + lane]);
    muLDS[lane] = mu0;
    muLDS[64 + lane] = mu1;
  }

  // ---- redistribute to the 2-rows-per-wave layout ----
  float sdr0[64], sdr1[64];               // s*D rows l and l+32
  {
    #pragma unroll
    for (int t = 0; t < 16; ++t) {
      f32x4 a = *(const f32x4*)&sdLDS[l * 68 + 4 * t];
      sdr0[4*t+0] = a.x; sdr0[4*t+1] = a.y; sdr0[4*t+2] = a.z; sdr0[4*t+3] = a.w;
    }
    #pragma unroll
    for (int t = 0; t < 16; ++t) {
      f32x4 a = *(const f32x4*)&sdLDS[(l + 32) * 68 + 4 * t];
      sdr1[4*t+0] = a.x; sdr1[4*t+1] = a.y; sdr1[4*t+2] = a.z; sdr1[4*t+3] = a.w;
    }
  }
  f32x4 hvr[16];                          // Hinv row l (output i = l of row g)
  #pragma unroll
  for (int t = 0; t < 16; ++t) hvr[t] = *(const f32x4*)&hiLDS[l * 68 + 4 * t];

  const float mua = muLDS[g * 64 + l];
  const float mub = muLDS[g * 64 + l + 32];
  const float bla = bmat[(size_t)rg * 64 + l];
  const float blb = bmat[(size_t)rg * 64 + l + 32];

  // ---- init: X0 = 0, rings primed (x1 = 0, x2 - b = -b) ----
  float* Xk = Xs + (size_t)rg * (ITERS + 1) * 128;
  float* obg = out2 + (size_t)rg * (ITERS + 1) * 32;
  Xk[l] = 0.f; Xk[l + 32] = 0.f; Xk[64 + l] = 0.f; Xk[96 + l] = 0.f;
  x1LDS[g * 64 + l] = 0.f;
  x1LDS[g * 64 + l + 32] = 0.f;
  x2LDS[g * 64 + l] = -bla;
  x2LDS[g * 64 + l + 32] = -blb;

  float x1a = 0.f, x1b = 0.f, x2a = 0.f, x2b = 0.f;

  // ================= main loop: k = 1..1000, primal one behind ==============
  #pragma unroll 1
  for (int k = 1; k <= ITERS; ++k) {
    // broadcast reads: each half-wave reads its row's vector (2-addr = free)
    f32x4 xc0 = *(const f32x4*)&x1LDS[g*64 +  0];
    f32x4 xc1 = *(const f32x4*)&x1LDS[g*64 +  4];
    f32x4 xc2 = *(const f32x4*)&x1LDS[g*64 +  8];
    f32x4 xc3 = *(const f32x4*)&x1LDS[g*64 + 12];
    f32x4 xc4 = *(const f32x4*)&x1LDS[g*64 + 16];
    f32x4 xc5 = *(const f32x4*)&x1LDS[g*64 + 20];
    f32x4 xc6 = *(const f32x4*)&x1LDS[g*64 + 24];
    f32x4 xc7 = *(const f32x4*)&x1LDS[g*64 + 28];
    f32x4 xc8 = *(const f32x4*)&x1LDS[g*64 + 32];
    f32x4 xc9 = *(const f32x4*)&x1LDS[g*64 + 36];
    f32x4 xcA = *(const f32x4*)&x1LDS[g*64 + 40];
    f32x4 xcB = *(const f32x4*)&x1LDS[g*64 + 44];
    f32x4 xcC = *(const f32x4*)&x1LDS[g*64 + 48];
    f32x4 xcD = *(const f32x4*)&x1LDS[g*64 + 52];
    f32x4 xcE = *(const f32x4*)&x1LDS[g*64 + 56];
    f32x4 xcF = *(const f32x4*)&x1LDS[g*64 + 60];
    f32x4 tb[16];
    #pragma unroll
    for (int t = 0; t < 16; ++t) tb[t] = *(const f32x4*)&x2LDS[g * 64 + 4 * t];

    // matvec: outputs i=l (oa) and i=l+32 (ob), 4 accumulators each
    float oa0, oa1, oa2, oa3, ob0, ob1, ob2, ob3;
    #define MV(T, xc)                                             \
      oa0 = fmaf(sdr0[4*T+0], xc.x, oa0);                         \
      oa1 = fmaf(sdr0[4*T+1], xc.y, oa1);                         \
      oa2 = fmaf(sdr0[4*T+2], xc.z, oa2);                         \
      oa3 = fmaf(sdr0[4*T+3], xc.w, oa3);                         \
      ob0 = fmaf(sdr1[4*T+0], xc.x, ob0);                         \
      ob1 = fmaf(sdr1[4*T+1], xc.y, ob1);                         \
      ob2 = fmaf(sdr1[4*T+2], xc.z, ob2);                         \
      ob3 = fmaf(sdr1[4*T+3], xc.w, ob3);
    oa0 = sdr0[0] * xc0.x; oa1 = sdr0[1] * xc0.y;
    oa2 = sdr0[2] * xc0.z; oa3 = sdr0[3] * xc0.w;
    ob0 = sdr1[0] * xc0.x; ob1 = sdr1[1] * xc0.y;
    ob2 = sdr1[2] * xc0.z; ob3 = sdr1[3] * xc0.w;
    MV(1, xc1)  MV(2, xc2)  MV(3, xc3)
    MV(4, xc4)  MV(5, xc5)  MV(6, xc6)  MV(7, xc7)
    MV(8, xc8)  MV(9, xc9)  MV(10, xcA) MV(11, xcB)
    MV(12, xcC) MV(13, xcD) MV(14, xcE) MV(15, xcF)
    #undef MV
    float x1na = ((oa0 + oa1) + (oa2 + oa3)) + fmaf(s, x2a, mua);
    float x1nb = ((ob0 + ob1) + (ob2 + ob3)) + fmaf(s, x2b, mub);
    float x2na = fmaxf(fmaf(-2.0f, x1na, x1a + x2a), 0.f);
    float x2nb = fmaxf(fmaf(-2.0f, x1nb, x1b + x2b), 0.f);

    // primal(k-1): full 64-term dot per lane (no cross-lane combine)
    f32x2 pa = {0.f, 0.f}, pb = {0.f, 0.f};
    #pragma unroll
    for (int t = 0; t < 16; ++t) {
      pa = fma2(hvr[t].xy, tb[t].xy, pa);
      pb = fma2(hvr[t].zw, tb[t].zw, pb);
    }
    obg[(size_t)(k - 1) * 32 + l] = (pa.x + pa.y) + (pb.x + pb.y);

    // ring writes for iteration k (after all reads of k-1 data: in-order DS)
    x1LDS[g * 64 + l] = x1na;
    x1LDS[g * 64 + l + 32] = x1nb;
    x2LDS[g * 64 + l] = x2na - bla;
    x2LDS[g * 64 + l + 32] = x2nb - blb;

    // Xs stores for iteration k
    Xk += 128;
    Xk[l] = x1na; Xk[l + 32] = x1nb;
    Xk[64 + l] = x2na; Xk[96 + l] = x2nb;

    x1a = x1na; x1b = x1nb; x2a = x2na; x2b = x2nb;
  }

  // tail: primal(1000) from the last ring write
  {
    f32x2 pa = {0.f, 0.f}, pb = {0.f, 0.f};
    #pragma unroll
    for (int t = 0; t < 16; ++t) {
      f32x4 tv = *(const f32x4*)&x2LDS[g * 64 + 4 * t];
      pa = fma2(hvr[t].xy, tv.xy, pa);
      pb = fma2(hvr[t].zw, tv.zw, pb);
    }
    obg[(size_t)ITERS * 32 + l] = (pa.x + pa.y) + (pb.x + pb.y);
  }
}

extern "C" void kernel_launch(void* const* d_in, const int* in_sizes, int n_in,
                              void* d_out, int out_size, void* d_ws, size_t ws_size,
                              hipStream_t stream) {
  (void)in_sizes; (void)n_in; (void)out_size; (void)d_ws; (void)ws_size;
  const float* q = (const float*)d_in[0];
  const float* b = (const float*)d_in[1];
  const float* P = (const float*)d_in[2];
  const float* H = (const float*)d_in[3];
  float* Xs = (float*)d_out;
  float* out2 = Xs + (size_t)BATCH * (ITERS + 1) * 128;

  fused_kernel<<<BATCH / 2, 64, 0, stream>>>(q, b, P, H, Xs, out2);
}

// Round 9
// 619.240 us; speedup vs baseline: 1.3804x; 1.3804x over previous
//
#include <hip/hip_runtime.h>
#include <math.h>

#define BATCH 512
#define ITERS 1000
#define PLEN 25      // iterations per phase
#define PHASES 40

typedef float f32x2 __attribute__((ext_vector_type(2)));
typedef float f32x4 __attribute__((ext_vector_type(4)));

// readlane requires a WAVE-UNIFORM lane index (all uses are constants here).
__device__ __forceinline__ float rdlane(float v, int l) {
  return __int_as_float(__builtin_amdgcn_readlane(__float_as_int(v), l));
}
__device__ __forceinline__ f32x2 fma2(f32x2 a, f32x2 b, f32x2 c) {
#if __has_builtin(__builtin_elementwise_fma)
  return __builtin_elementwise_fma(a, b, c);
#else
  f32x2 r; r.x = fmaf(a.x, b.x, c.x); r.y = fmaf(a.y, b.y, c.y); return r;
#endif
}

// Register-resident Gauss-Jordan on [A|I] (32x64); lane holds column `lane`.
#define GJ32_REG(g)                                            \
  _Pragma("unroll")                                            \
  for (int k = 0; k < 32; ++k) {                               \
    float inv = 1.0f / rdlane(g[k], k);                        \
    g[k] *= inv;                                               \
    _Pragma("unroll")                                          \
    for (int ii = 0; ii < 32; ++ii) {                          \
      if (ii == k) continue;                                   \
      float f = rdlane(g[ii], k);                              \
      g[ii] = fmaf(-f, g[k], g[ii]);                           \
    }                                                          \
  }

// ONE 4-wave block per CU, handling TWO rows:
//   wave 0 -> producer row 2B      (SIMD0)   wave 1 -> producer row 2B+1 (SIMD1)
//   wave 2 -> consumer row 2B      (SIMD2)   wave 3 -> consumer row 2B+1 (SIMD3)
// HW assigns block waves round-robin across SIMDs, so each producer owns its
// SIMD exclusively (the r6/r7 871-vs-578 cyc/iter gap is attributed to two
// co-resident blocks stacking producers on one SIMD). Producers are pure
// VALU + 2 ds_writes/iter; consumers do all global stores + primal GEMV.
__global__ __launch_bounds__(256, 1)
void fused_kernel(const float* __restrict__ q,
                  const float* __restrict__ bmat,
                  const float* __restrict__ P,
                  const float* __restrict__ H,
                  float* __restrict__ Xs,
                  float* __restrict__ out2) {
  __shared__ __align__(16) float stage[2112];                 // Hl 64x33 -> HT 32x66
  __shared__ __align__(16) float X1R[2][2][PLEN][64];         // [row][buf][slot][comp]
  __shared__ __align__(16) float X2R[2][2][PLEN][64];         // x2 - b

  const int tid = threadIdx.x;
  const int wv = tid >> 6;                 // 0,1 producers; 2,3 consumers
  const int lane = tid & 63;
  const int rib = wv & 1;                  // row-in-block
  const bool prod = (wv < 2);
  const int rg = 2 * blockIdx.x + rib;
  const int i = lane & 31, h = lane >> 5;

  // ---- H row `lane` (producers: setup; consumers: Hinv build) ----
  float hreg[32];
  {
    const f32x4* hp = (const f32x4*)(H + lane * 32);
    #pragma unroll
    for (int j4 = 0; j4 < 8; ++j4) {
      f32x4 t = hp[j4];
      hreg[4*j4+0] = t.x; hreg[4*j4+1] = t.y; hreg[4*j4+2] = t.z; hreg[4*j4+3] = t.w;
    }
  }
  const float bl = bmat[(size_t)rg * 64 + lane];

  float dcol[64]; float s = 0.f, mu = 0.f;        // producer state
  f32x2 hv2[16];                                  // consumer state
  float* Xp = Xs + (size_t)rg * (ITERS + 1) * 128;
  float* ob = out2 + (size_t)rg * (ITERS + 1) * 32;

  // ---------- consumer-side Hinv build (stage written by wave 2 only) -------
  if (wv == 2) {
    #pragma unroll
    for (int j = 0; j < 32; ++j) stage[lane * 33 + j] = hreg[j];
  }
  __syncthreads();                                // B1
  float gB[32];
  if (!prod) {
    float htc[64];                                // htc[m] = H[m][i]
    #pragma unroll
    for (int m = 0; m < 64; ++m) htc[m] = stage[m * 33 + i];
    #pragma unroll
    for (int r = 0; r < 32; ++r) {
      float a0 = 0.f, a1 = 0.f;
      #pragma unroll
      for (int m = 0; m < 64; m += 2) {
        a0 = fmaf(rdlane(hreg[r], m),     htc[m],     a0);
        a1 = fmaf(rdlane(hreg[r], m + 1), htc[m + 1], a1);
      }
      float hth = a0 + a1;                        // (H^T H)[r][i]
      gB[r] = (lane < 32) ? hth : (((lane - 32) == r) ? 1.0f : 0.0f);
    }
    GJ32_REG(gB)
  }
  __syncthreads();                                // B2
  if (wv == 2) {
    #pragma unroll
    for (int r = 0; r < 32; ++r) {                // Hinv[r][lane] -> staging
      float a0 = 0.f, a1 = 0.f;
      #pragma unroll
      for (int c = 0; c < 32; c += 2) {
        a0 = fmaf(rdlane(gB[r], 32 + c),     hreg[c],     a0);
        a1 = fmaf(rdlane(gB[r], 32 + c + 1), hreg[c + 1], a1);
      }
      stage[r * 66 + lane] = a0 + a1;
    }
  }
  __syncthreads();                                // B3
  if (!prod) {
    #pragma unroll
    for (int t = 0; t < 16; ++t)                  // lane (h,i): Hinv[i][32h+2t..+1]
      hv2[t] = *(const f32x2*)&stage[i * 66 + 32 * h + 2 * t];
  }

  if (prod) {
    // ---------- producer setup (registers only) ----------
    float pht[32], acc;
    {
      float g[32];
      #pragma unroll
      for (int r = 0; r < 32; ++r) {
        float pv = P[r * 32 + i];
        g[r] = (lane < 32) ? pv : (((lane - 32) == r) ? 1.0f : 0.0f);
      }
      GJ32_REG(g)
      #pragma unroll
      for (int r = 0; r < 32; ++r) {      // (P^-1 H^T)[r][lane]
        float a0 = 0.f, a1 = 0.f;
        #pragma unroll
        for (int j = 0; j < 32; j += 2) {
          a0 = fmaf(rdlane(g[r], 32 + j),     hreg[j],     a0);
          a1 = fmaf(rdlane(g[r], 32 + j + 1), hreg[j + 1], a1);
        }
        pht[r] = a0 + a1;
      }
    }
    {
      const float* qp = q + (size_t)rg * 32;       // wave-uniform -> s_loads
      float a0 = 0.f, a1 = 0.f;
      #pragma unroll
      for (int r = 0; r < 32; r += 2) {
        a0 = fmaf(qp[r],     pht[r],     a0);
        a1 = fmaf(qp[r + 1], pht[r + 1], a1);
      }
      acc = a0 + a1;                      // (H P^-1 q)[lane]
    }
    #pragma unroll
    for (int r = 0; r < 64; ++r) {        // D[r][lane] (symmetric)
      float a0 = 0.f, a1 = 0.f;
      #pragma unroll
      for (int j = 0; j < 32; j += 2) {
        a0 = fmaf(rdlane(hreg[j],     r), pht[j],     a0);
        a1 = fmaf(rdlane(hreg[j + 1], r), pht[j + 1], a1);
      }
      dcol[r] = a0 + a1;
    }
    {
      float ecol[64];                     // E = D^2 (squares convergence rate)
      #pragma unroll
      for (int r = 0; r < 64; ++r) {
        float a0 = 0.f, a1 = 0.f;
        #pragma unroll
        for (int c = 0; c < 64; c += 2) {
          a0 = fmaf(rdlane(dcol[r], c),     dcol[c],     a0);
          a1 = fmaf(rdlane(dcol[r], c + 1), dcol[c + 1], a1);
        }
        ecol[r] = a0 + a1;
      }
      float v = 1.0f + 0.017f * (float)lane;
      #pragma unroll 1
      for (int t = 0; t < 112; ++t) {
        float a0 = 0.f, a1 = 0.f, a2 = 0.f, a3 = 0.f;
        #pragma unroll
        for (int c = 0; c < 64; c += 4) {
          a0 = fmaf(ecol[c+0], rdlane(v, c+0), a0);
          a1 = fmaf(ecol[c+1], rdlane(v, c+1), a1);
          a2 = fmaf(ecol[c+2], rdlane(v, c+2), a2);
          a3 = fmaf(ecol[c+3], rdlane(v, c+3), a3);
        }
        v = (a0 + a1) + (a2 + a3);
        if ((t & 7) == 7) {
          float n2 = v * v;
          #pragma unroll
          for (int m = 1; m < 64; m <<= 1) n2 += __shfl_xor(n2, m);
          v *= 1.0f / sqrtf(n2);
        }
      }
      float a0 = 0.f, a1 = 0.f, a2 = 0.f, a3 = 0.f;  // Rayleigh with D
      #pragma unroll
      for (int c = 0; c < 64; c += 4) {
        a0 = fmaf(dcol[c+0], rdlane(v, c+0), a0);
        a1 = fmaf(dcol[c+1], rdlane(v, c+1), a1);
        a2 = fmaf(dcol[c+2], rdlane(v, c+2), a2);
        a3 = fmaf(dcol[c+3], rdlane(v, c+3), a3);
      }
      float w = (a0 + a1) + (a2 + a3);
      float num = w * v, den = v * v;
      #pragma unroll
      for (int m = 1; m < 64; m <<= 1) {
        num += __shfl_xor(num, m);
        den += __shfl_xor(den, m);
      }
      s = den / num;                      // s = 1 / lambda_max(D)
    }
    mu = s * (acc - bl);
    #pragma unroll
    for (int r = 0; r < 64; ++r) dcol[r] *= s;   // row `lane` of s*D
  }

  // ---------- main loop: 40 phases x 25 iterations ----------
  float x1 = 0.f, x2 = 0.f;
  #pragma unroll 1
  for (int p = 0; p < PHASES; ++p) {
    if (prod) {
      float* rx1 = &X1R[rib][p & 1][0][0];
      float* rx2 = &X2R[rib][p & 1][0][0];
      #pragma unroll 1
      for (int u = 0; u < PLEN; ++u) {
        float a0 = 0.f, a1 = 0.f, a2 = 0.f, a3 = 0.f;
        #pragma unroll
        for (int j8 = 0; j8 < 64; j8 += 8) {
          float b0 = rdlane(x1, j8+0), b1 = rdlane(x1, j8+1);
          float b2 = rdlane(x1, j8+2), b3 = rdlane(x1, j8+3);
          float b4 = rdlane(x1, j8+4), b5 = rdlane(x1, j8+5);
          float b6 = rdlane(x1, j8+6), b7 = rdlane(x1, j8+7);
          a0 = fmaf(dcol[j8+0], b0, a0);
          a1 = fmaf(dcol[j8+1], b1, a1);
          a2 = fmaf(dcol[j8+2], b2, a2);
          a3 = fmaf(dcol[j8+3], b3, a3);
          a0 = fmaf(dcol[j8+4], b4, a0);
          a1 = fmaf(dcol[j8+5], b5, a1);
          a2 = fmaf(dcol[j8+6], b6, a2);
          a3 = fmaf(dcol[j8+7], b7, a3);
        }
        float x1n = ((a0 + a1) + (a2 + a3)) + fmaf(s, x2, mu);
        float x2n = fmaxf(fmaf(-2.0f, x1n, x1 + x2), 0.f);
        rx1[u * 64 + lane] = x1n;
        rx2[u * 64 + lane] = x2n - bl;
        x1 = x1n; x2 = x2n;
      }
    } else {
      if (p == 0) {
        // k = 0: X0 = 0 stores + primal_0 = Hinv @ (-b)
        Xp[lane] = 0.f;
        Xp[64 + lane] = 0.f;
        f32x2 pa = {0.f, 0.f}, pb = {0.f, 0.f};
        #pragma unroll
        for (int t = 0; t < 8; ++t) {
          f32x2 ta, tb;
          ta.x = -__shfl(bl, 32*h + 4*t + 0, 64);   // divergent idx -> __shfl
          ta.y = -__shfl(bl, 32*h + 4*t + 1, 64);
          tb.x = -__shfl(bl, 32*h + 4*t + 2, 64);
          tb.y = -__shfl(bl, 32*h + 4*t + 3, 64);
          pa = fma2(hv2[2*t],     ta, pa);
          pb = fma2(hv2[2*t + 1], tb, pb);
        }
        float pr = (pa.x + pa.y) + (pb.x + pb.y);
        pr += __shfl_xor(pr, 32);
        if (h == 0) ob[i] = pr;
      } else {
        const float* rx1 = &X1R[rib][(p - 1) & 1][0][0];
        const float* rx2 = &X2R[rib][(p - 1) & 1][0][0];
        const int k0 = PLEN * (p - 1) + 1;
        float* Xk = Xp + (size_t)k0 * 128;
        float* obk = ob + (size_t)k0 * 32;
        #pragma unroll 1
        for (int u = 0; u < PLEN; ++u) {
          float x1v = rx1[u * 64 + lane];
          float x2mb = rx2[u * 64 + lane];
          Xk[u * 128 + lane] = x1v;
          Xk[u * 128 + 64 + lane] = x2mb + bl;
          const f32x4* tp = (const f32x4*)(rx2 + u * 64 + h * 32);
          f32x2 pa = {0.f, 0.f}, pb = {0.f, 0.f};
          #pragma unroll
          for (int t = 0; t < 8; ++t) {
            f32x4 tv = tp[t];
            pa = fma2(hv2[2*t],     tv.xy, pa);
            pb = fma2(hv2[2*t + 1], tv.zw, pb);
          }
          float pr = (pa.x + pa.y) + (pb.x + pb.y);
          pr += __shfl_xor(pr, 32);
          if (h == 0) obk[u * 32 + i] = pr;
        }
      }
    }
    __syncthreads();                      // all 4 waves, every phase
  }

  if (!prod) {
    // tail: phase 39 data (buffer 1), k = 976..1000
    const float* rx1 = &X1R[rib][1][0][0];
    const float* rx2 = &X2R[rib][1][0][0];
    const int k0 = PLEN * (PHASES - 1) + 1;
    float* Xk = Xp + (size_t)k0 * 128;
    float* obk = ob + (size_t)k0 * 32;
    #pragma unroll 1
    for (int u = 0; u < PLEN; ++u) {
      float x1v = rx1[u * 64 + lane];
      float x2mb = rx2[u * 64 + lane];
      Xk[u * 128 + lane] = x1v;
      Xk[u * 128 + 64 + lane] = x2mb + bl;
      const f32x4* tp = (const f32x4*)(rx2 + u * 64 + h * 32);
      f32x2 pa = {0.f, 0.f}, pb = {0.f, 0.f};
      #pragma unroll
      for (int t = 0; t < 8; ++t) {
        f32x4 tv = tp[t];
        pa = fma2(hv2[2*t],     tv.xy, pa);
        pb = fma2(hv2[2*t + 1], tv.zw, pb);
      }
      float pr = (pa.x + pa.y) + (pb.x + pb.y);
      pr += __shfl_xor(pr, 32);
      if (h == 0) obk[u * 32 + i] = pr;
    }
  }
}

extern "C" void kernel_launch(void* const* d_in, const int* in_sizes, int n_in,
                              void* d_out, int out_size, void* d_ws, size_t ws_size,
                              hipStream_t stream) {
  (void)in_sizes; (void)n_in; (void)out_size; (void)d_ws; (void)ws_size;
  const float* q = (const float*)d_in[0];
  const float* b = (const float*)d_in[1];
  const float* P = (const float*)d_in[2];
  const float* H = (const float*)d_in[3];
  float* Xs = (float*)d_out;
  float* out2 = Xs + (size_t)BATCH * (ITERS + 1) * 128;

  fused_kernel<<<BATCH / 2, 256, 0, stream>>>(q, b, P, H, Xs, out2);
}